// Round 1
// baseline (143.278 us; speedup 1.0000x reference)
//
#include <hip/hip_runtime.h>
#include <stdint.h>

// out = tokens @ W_eff + b_eff, where W_eff folds the BULK_DIM=10 depth
// dimension with closed-form weights w_k = (1/10) * sum_{z=k..10} 1/z.
// The reference scan g_z = g_{z-1} + (1/z)(c_z - g_{z-1}) starting at c_1 is
// the running mean; mean over z gives these weights (sum w_k == 1).

static constexpr float FW[10] = {
    0.2928968253968254f, 0.1928968253968254f, 0.1428968253968254f,
    0.1095634920634921f, 0.0845634920634921f, 0.0645634920634921f,
    0.0478968253968254f, 0.0336111111111111f, 0.0211111111111111f,
    0.0100000000000000f};

typedef __attribute__((ext_vector_type(8))) short short8;   // 8 bf16 = 4 VGPR
typedef __attribute__((ext_vector_type(4))) float floatx4;  // MFMA C/D frag

// round-to-nearest fp32->bf16, pack two into one uint via v_perm_b32
__device__ inline unsigned int bf16pack2(float hi, float lo) {
    unsigned int uh = __float_as_uint(hi) + 0x8000u;
    unsigned int ul = __float_as_uint(lo) + 0x8000u;
    return __builtin_amdgcn_perm(uh, ul, 0x07060302u);  // {hi[31:16], lo[31:16]}
}

#define LDS_AS(p) ((__attribute__((address_space(3))) unsigned int*)(p))
#define GLB_AS(p) ((const __attribute__((address_space(1))) unsigned int*)(p))

// ---------------------------------------------------------------------------
// Kernel 1: W_eff^T[n][k] = sum_j FW[j] * W[k][j*1024 + n], bf16, n-major
// (K-contiguous rows so the GEMM can global_load_lds B tiles).
// 64x64 (k,n) tiles, LDS transpose, both global sides coalesced.
// ---------------------------------------------------------------------------
__global__ __launch_bounds__(256) void fold_w(const float* __restrict__ W,
                                              unsigned short* __restrict__ Wt) {
    __shared__ float T[64 * 65];  // stride 65: transposed reads are 2-way max
    const int t = threadIdx.x;
    const int n0 = blockIdx.x * 64;
    const int k0 = blockIdx.y * 64;

#pragma unroll
    for (int s = 0; s < 4; ++s) {
        int slot = s * 256 + t;
        int r = slot >> 4;              // k-local 0..63
        int c4 = (slot & 15) * 4;       // n-local float4
        const float4* src = (const float4*)(W + (size_t)(k0 + r) * 10240 + n0 + c4);
        float4 acc = {0.f, 0.f, 0.f, 0.f};
#pragma unroll
        for (int j = 0; j < 10; ++j) {
            float4 v = src[j * 256];    // advance j*1024 floats
            acc.x += FW[j] * v.x; acc.y += FW[j] * v.y;
            acc.z += FW[j] * v.z; acc.w += FW[j] * v.w;
        }
        T[r * 65 + c4 + 0] = acc.x;
        T[r * 65 + c4 + 1] = acc.y;
        T[r * 65 + c4 + 2] = acc.z;
        T[r * 65 + c4 + 3] = acc.w;
    }
    __syncthreads();
#pragma unroll
    for (int s = 0; s < 4; ++s) {
        int slot = s * 256 + t;
        int nl = slot >> 4;             // n-local 0..63
        int k4 = (slot & 15) * 4;       // k-local float4
        float f0 = T[(k4 + 0) * 65 + nl];
        float f1 = T[(k4 + 1) * 65 + nl];
        float f2 = T[(k4 + 2) * 65 + nl];
        float f3 = T[(k4 + 3) * 65 + nl];
        uint2 p;
        p.x = bf16pack2(f1, f0);
        p.y = bf16pack2(f3, f2);
        *(uint2*)(Wt + (size_t)(n0 + nl) * 1024 + k0 + k4) = p;  // coalesced 8B
    }
}

// ---------------------------------------------------------------------------
// Kernel 2: b_eff[n] = sum_j FW[j] * b[j*1024 + n]  (fp32, 1024 values)
// ---------------------------------------------------------------------------
__global__ __launch_bounds__(256) void fold_b(const float* __restrict__ b,
                                              float* __restrict__ beff) {
    const int t = threadIdx.x;
    const float4* src = (const float4*)b + t;  // b + 4t
    float4 acc = {0.f, 0.f, 0.f, 0.f};
#pragma unroll
    for (int j = 0; j < 10; ++j) {
        float4 v = src[j * 256];
        acc.x += FW[j] * v.x; acc.y += FW[j] * v.y;
        acc.z += FW[j] * v.z; acc.w += FW[j] * v.w;
    }
    ((float4*)beff)[t] = acc;
}

// ---------------------------------------------------------------------------
// Kernel 3: C[8192][1024] = A[8192][1024](fp32->bf16) @ Weff^T + b_eff
// 128x128 block tile, 4 waves in 2x2, each wave 4x4 mfma_f32_16x16x32_bf16,
// BK=64. A: register-staged (cvt) into padded LDS (stride 72 shorts).
// B: global_load_lds width=16 with XOR swizzle slot = n*8 + (c ^ (n&7)).
// ---------------------------------------------------------------------------
__global__ __launch_bounds__(256) void gemm_bf16(const float* __restrict__ A,
                                                 const unsigned short* __restrict__ Wt,
                                                 const float* __restrict__ beff,
                                                 float* __restrict__ C) {
    __shared__ __align__(16) unsigned short As[128 * 72];  // 18432 B, pad +8
    __shared__ __align__(16) unsigned char Bs[16384];      // 128 rows x 8 slots x 16B

    const int t = threadIdx.x;
    const int lane = t & 63;
    const int w = t >> 6;          // wave 0..3
    const int quad = lane >> 4;    // 0..3
    const int l15 = lane & 15;
    const int wm = (w & 1) * 64;   // wave M offset in tile
    const int wn = (w >> 1) * 64;  // wave N offset in tile
    const int bm = blockIdx.y * 128;
    const int bn = blockIdx.x * 128;

    floatx4 acc[4][4];
#pragma unroll
    for (int i = 0; i < 4; ++i)
#pragma unroll
        for (int j = 0; j < 4; ++j) acc[i][j] = (floatx4){0.f, 0.f, 0.f, 0.f};

    // A staging map: thread -> (row ar within 16-row sweep, float4 col ac4)
    const int ar = t >> 4;               // 0..15
    const int ac4 = (t & 15) * 4;        // 0,4,...,60
    const float* Abase = A + (size_t)(bm + ar) * 1024 + ac4;
    const char* WtB = (const char*)Wt;

    for (int k0 = 0; k0 < 1024; k0 += 64) {
        // --- B tile: async global->LDS, 16 x 1KB instructions (4 per wave)
#pragma unroll
        for (int i = 0; i < 4; ++i) {
            int I = w * 4 + i;
            int slot = I * 64 + lane;
            int nl = slot >> 3;          // n-local 0..127
            int cs = slot & 7;           // physical chunk
            int c = cs ^ (nl & 7);       // logical k-chunk (XOR swizzle)
            const char* g = WtB + (size_t)(bn + nl) * 2048 + k0 * 2 + c * 16;
            __builtin_amdgcn_global_load_lds(GLB_AS(g), LDS_AS(Bs + I * 1024), 16, 0, 0);
        }
        // --- A tile: fp32 loads -> bf16 pack -> LDS (8 sweeps of 16 rows)
        float4 av[8];
#pragma unroll
        for (int s = 0; s < 8; ++s)
            av[s] = *(const float4*)(Abase + (size_t)(s * 16) * 1024 + k0);
#pragma unroll
        for (int s = 0; s < 8; ++s) {
            uint2 p;
            p.x = bf16pack2(av[s].y, av[s].x);
            p.y = bf16pack2(av[s].w, av[s].z);
            *(uint2*)((char*)As + (size_t)(s * 16 + ar) * 144 + ac4 * 2) = p;
        }
        __syncthreads();

        // --- compute: 2 K-steps of 32
#pragma unroll
        for (int kk = 0; kk < 2; ++kk) {
            short8 af[4], bf[4];
#pragma unroll
            for (int tm = 0; tm < 4; ++tm) {
                int m = wm + tm * 16 + l15;
                af[tm] = *(const short8*)((const char*)As + (size_t)m * 144 + kk * 64 + quad * 16);
            }
#pragma unroll
            for (int tn = 0; tn < 4; ++tn) {
                int n = wn + tn * 16 + l15;
                int c = kk * 4 + quad;
                int slot = n * 8 + (c ^ (n & 7));
                bf[tn] = *(const short8*)(Bs + slot * 16);
            }
#pragma unroll
            for (int tm = 0; tm < 4; ++tm)
#pragma unroll
                for (int tn = 0; tn < 4; ++tn)
                    acc[tm][tn] = __builtin_amdgcn_mfma_f32_16x16x32_bf16(
                        af[tm], bf[tn], acc[tm][tn], 0, 0, 0);
        }
        __syncthreads();
    }

    // --- epilogue: C/D layout col = lane&15, row = quad*4 + reg
#pragma unroll
    for (int tn = 0; tn < 4; ++tn) {
        int col = bn + wn + tn * 16 + l15;
        float bias = beff[col];
#pragma unroll
        for (int tm = 0; tm < 4; ++tm) {
            int row0 = bm + wm + tm * 16 + quad * 4;
#pragma unroll
            for (int r = 0; r < 4; ++r)
                C[(size_t)(row0 + r) * 1024 + col] = acc[tm][tn][r] + bias;
        }
    }
}

extern "C" void kernel_launch(void* const* d_in, const int* in_sizes, int n_in,
                              void* d_out, int out_size, void* d_ws, size_t ws_size,
                              hipStream_t stream) {
    const float* tokens = (const float*)d_in[0];  // (4,2048,1024) fp32
    const float* W      = (const float*)d_in[1];  // (1024, 10240) fp32
    const float* b      = (const float*)d_in[2];  // (10240,) fp32
    float* out = (float*)d_out;                   // (4,2048,1024) fp32

    unsigned short* Wt = (unsigned short*)d_ws;                   // 2 MB bf16
    float* beff = (float*)((char*)d_ws + 1024 * 1024 * 2);        // 4 KB fp32

    fold_w<<<dim3(16, 16), 256, 0, stream>>>(W, Wt);
    fold_b<<<1, 256, 0, stream>>>(b, beff);
    gemm_bf16<<<dim3(8, 64), 256, 0, stream>>>(tokens, Wt, beff, out);
}

// Round 2
// 135.812 us; speedup vs baseline: 1.0550x; 1.0550x over previous
//
#include <hip/hip_runtime.h>
#include <stdint.h>

// out = tokens @ W_eff + b_eff, where W_eff folds the BULK_DIM=10 depth
// dimension with closed-form weights w_k = (1/10) * sum_{z=k..10} 1/z.
// (The reference scan is the running mean; averaging over depth gives these.)

static constexpr float FW[10] = {
    0.2928968253968254f, 0.1928968253968254f, 0.1428968253968254f,
    0.1095634920634921f, 0.0845634920634921f, 0.0645634920634921f,
    0.0478968253968254f, 0.0336111111111111f, 0.0211111111111111f,
    0.0100000000000000f};

typedef __attribute__((ext_vector_type(8))) short short8;   // 8 bf16 = 4 VGPR
typedef __attribute__((ext_vector_type(4))) float floatx4;  // MFMA C/D frag

// round-to-nearest fp32->bf16, pack two into one uint via v_perm_b32
__device__ inline unsigned int bf16pack2(float hi, float lo) {
    unsigned int uh = __float_as_uint(hi) + 0x8000u;
    unsigned int ul = __float_as_uint(lo) + 0x8000u;
    return __builtin_amdgcn_perm(uh, ul, 0x07060302u);  // {hi[31:16], lo[31:16]}
}

#define LDS_AS(p) ((__attribute__((address_space(3))) unsigned int*)(p))
#define GLB_AS(p) ((const __attribute__((address_space(1))) unsigned int*)(p))

// ---------------------------------------------------------------------------
// Kernel 1: W_eff^T[n][k] = sum_j FW[j] * W[k][j*1024 + n], bf16, n-major
// (K-contiguous rows so the GEMM can global_load_lds B tiles).
// 32(k) x 64(n) tiles, LDS transpose; grid (16,32) = 512 blocks.
// ---------------------------------------------------------------------------
__global__ __launch_bounds__(256) void fold_w(const float* __restrict__ W,
                                              unsigned short* __restrict__ Wt) {
    __shared__ float T[32 * 65];
    const int t = threadIdx.x;
    const int n0 = blockIdx.x * 64;
    const int k0 = blockIdx.y * 32;

#pragma unroll
    for (int s = 0; s < 2; ++s) {
        int slot = s * 256 + t;
        int r = slot >> 4;              // k-local 0..31
        int c4 = (slot & 15) * 4;       // n-local float4
        const float4* src = (const float4*)(W + (size_t)(k0 + r) * 10240 + n0 + c4);
        float4 acc = {0.f, 0.f, 0.f, 0.f};
#pragma unroll
        for (int j = 0; j < 10; ++j) {
            float4 v = src[j * 256];    // advance j*1024 floats
            acc.x += FW[j] * v.x; acc.y += FW[j] * v.y;
            acc.z += FW[j] * v.z; acc.w += FW[j] * v.w;
        }
        T[r * 65 + c4 + 0] = acc.x;
        T[r * 65 + c4 + 1] = acc.y;
        T[r * 65 + c4 + 2] = acc.z;
        T[r * 65 + c4 + 3] = acc.w;
    }
    __syncthreads();
#pragma unroll
    for (int s = 0; s < 2; ++s) {
        int slot = s * 256 + t;
        int nl = slot >> 3;             // n-local 0..63
        int k4 = (slot & 7) * 4;        // k-local group of 4
        float f0 = T[(k4 + 0) * 65 + nl];
        float f1 = T[(k4 + 1) * 65 + nl];
        float f2 = T[(k4 + 2) * 65 + nl];
        float f3 = T[(k4 + 3) * 65 + nl];
        uint2 p;
        p.x = bf16pack2(f1, f0);
        p.y = bf16pack2(f3, f2);
        *(uint2*)(Wt + (size_t)(n0 + nl) * 1024 + k0 + k4) = p;  // coalesced 8B
    }
}

// ---------------------------------------------------------------------------
// Kernel 2: b_eff[n] = sum_j FW[j] * b[j*1024 + n]  (fp32, 1024 values)
// ---------------------------------------------------------------------------
__global__ __launch_bounds__(256) void fold_b(const float* __restrict__ b,
                                              float* __restrict__ beff) {
    const int t = threadIdx.x;
    const float4* src = (const float4*)b + t;
    float4 acc = {0.f, 0.f, 0.f, 0.f};
#pragma unroll
    for (int j = 0; j < 10; ++j) {
        float4 v = src[j * 256];
        acc.x += FW[j] * v.x; acc.y += FW[j] * v.y;
        acc.z += FW[j] * v.z; acc.w += FW[j] * v.w;
    }
    ((float4*)beff)[t] = acc;
}

// ---------------------------------------------------------------------------
// Kernel 3: tokens fp32 -> bf16 row-major (8M elements, 8 per thread)
// ---------------------------------------------------------------------------
__global__ __launch_bounds__(256) void cvt_bf16(const float* __restrict__ A,
                                                uint4* __restrict__ Ab) {
    size_t i = (size_t)blockIdx.x * 256 + threadIdx.x;
    const float4* src = (const float4*)A + i * 2;
    float4 a0 = src[0], a1 = src[1];
    uint4 p;
    p.x = bf16pack2(a0.y, a0.x);
    p.y = bf16pack2(a0.w, a0.z);
    p.z = bf16pack2(a1.y, a1.x);
    p.w = bf16pack2(a1.w, a1.z);
    Ab[i] = p;
}

// ---------------------------------------------------------------------------
// Kernel 4: C[8192][1024] = Ab(bf16) @ Weff^T + b_eff
// 128x128 tile, 4 waves 2x2, each 4x4 mfma_f32_16x16x32_bf16, BK=64.
// Both operands staged via global_load_lds width=16 with XOR swizzle
// slot = row*8 + (chunk ^ (row&7)) -> fragment ds_read_b128 is 2-way (free).
// Grid (64,8), x = M-tile: block-id%8 = bm%8 -> A stripes pinned per XCD;
// per-XCD working set = 2MB A-stripes + 2MB B, resident in 4MB L2.
// ---------------------------------------------------------------------------
__global__ __launch_bounds__(256) void gemm_bf16(const unsigned short* __restrict__ Ab,
                                                 const unsigned short* __restrict__ Wt,
                                                 const float* __restrict__ beff,
                                                 float* __restrict__ C) {
    __shared__ __align__(16) unsigned char As[16384];  // 128 rows x 8 slots x 16B
    __shared__ __align__(16) unsigned char Bs[16384];

    const int t = threadIdx.x;
    const int lane = t & 63;
    const int w = t >> 6;
    const int quad = lane >> 4;
    const int l15 = lane & 15;
    const int wm = (w & 1) * 64;
    const int wn = (w >> 1) * 64;
    const int bm = blockIdx.x * 128;   // x fastest -> id%8 = bm-tile%8 (XCD pin)
    const int bn = blockIdx.y * 128;

    floatx4 acc[4][4];
#pragma unroll
    for (int i = 0; i < 4; ++i)
#pragma unroll
        for (int j = 0; j < 4; ++j) acc[i][j] = (floatx4){0.f, 0.f, 0.f, 0.f};

    const char* Abase = (const char*)Ab + (size_t)bm * 2048;
    const char* Bbase = (const char*)Wt + (size_t)bn * 2048;

    for (int k0 = 0; k0 < 1024; k0 += 64) {
#pragma unroll
        for (int i = 0; i < 4; ++i) {
            int I = w * 4 + i;              // 0..15
            int slot = I * 64 + lane;       // physical 16B slot 0..1023
            int m = slot >> 3;              // tile row 0..127
            int c = (slot & 7) ^ (m & 7);   // logical k-chunk (XOR swizzle)
            size_t off = (size_t)m * 2048 + (size_t)k0 * 2 + c * 16;
            __builtin_amdgcn_global_load_lds(GLB_AS(Abase + off), LDS_AS(As + I * 1024), 16, 0, 0);
            __builtin_amdgcn_global_load_lds(GLB_AS(Bbase + off), LDS_AS(Bs + I * 1024), 16, 0, 0);
        }
        __syncthreads();

#pragma unroll
        for (int kk = 0; kk < 2; ++kk) {
            short8 af[4], bf[4];
            int c = kk * 4 + quad;
#pragma unroll
            for (int tm = 0; tm < 4; ++tm) {
                int m = wm + tm * 16 + l15;
                int slot = m * 8 + (c ^ (m & 7));
                af[tm] = *(const short8*)(As + slot * 16);
            }
#pragma unroll
            for (int tn = 0; tn < 4; ++tn) {
                int n = wn + tn * 16 + l15;
                int slot = n * 8 + (c ^ (n & 7));
                bf[tn] = *(const short8*)(Bs + slot * 16);
            }
#pragma unroll
            for (int tm = 0; tm < 4; ++tm)
#pragma unroll
                for (int tn = 0; tn < 4; ++tn)
                    acc[tm][tn] = __builtin_amdgcn_mfma_f32_16x16x32_bf16(
                        af[tm], bf[tn], acc[tm][tn], 0, 0, 0);
        }
        __syncthreads();
    }

    // epilogue: C/D layout col = lane&15, row = quad*4 + reg
#pragma unroll
    for (int tn = 0; tn < 4; ++tn) {
        int col = bn + wn + tn * 16 + l15;
        float bias = beff[col];
#pragma unroll
        for (int tm = 0; tm < 4; ++tm) {
            int row0 = bm + wm + tm * 16 + quad * 4;
#pragma unroll
            for (int r = 0; r < 4; ++r)
                C[(size_t)(row0 + r) * 1024 + col] = acc[tm][tn][r] + bias;
        }
    }
}

// ---------------------------------------------------------------------------
// Fallback GEMM (R1 version, fp32 A converted in-kernel) for small ws_size.
// ---------------------------------------------------------------------------
__global__ __launch_bounds__(256) void gemm_fb(const float* __restrict__ A,
                                               const unsigned short* __restrict__ Wt,
                                               const float* __restrict__ beff,
                                               float* __restrict__ C) {
    __shared__ __align__(16) unsigned short As[128 * 72];
    __shared__ __align__(16) unsigned char Bs[16384];

    const int t = threadIdx.x;
    const int lane = t & 63;
    const int w = t >> 6;
    const int quad = lane >> 4;
    const int l15 = lane & 15;
    const int wm = (w & 1) * 64;
    const int wn = (w >> 1) * 64;
    const int bm = blockIdx.y * 128;
    const int bn = blockIdx.x * 128;

    floatx4 acc[4][4];
#pragma unroll
    for (int i = 0; i < 4; ++i)
#pragma unroll
        for (int j = 0; j < 4; ++j) acc[i][j] = (floatx4){0.f, 0.f, 0.f, 0.f};

    const int ar = t >> 4;
    const int ac4 = (t & 15) * 4;
    const float* Abase = A + (size_t)(bm + ar) * 1024 + ac4;
    const char* WtB = (const char*)Wt;

    for (int k0 = 0; k0 < 1024; k0 += 64) {
#pragma unroll
        for (int i = 0; i < 4; ++i) {
            int I = w * 4 + i;
            int slot = I * 64 + lane;
            int nl = slot >> 3;
            int c = (slot & 7) ^ (nl & 7);
            const char* g = WtB + (size_t)(bn + nl) * 2048 + k0 * 2 + c * 16;
            __builtin_amdgcn_global_load_lds(GLB_AS(g), LDS_AS(Bs + I * 1024), 16, 0, 0);
        }
        float4 av[8];
#pragma unroll
        for (int s = 0; s < 8; ++s)
            av[s] = *(const float4*)(Abase + (size_t)(s * 16) * 1024 + k0);
#pragma unroll
        for (int s = 0; s < 8; ++s) {
            uint2 p;
            p.x = bf16pack2(av[s].y, av[s].x);
            p.y = bf16pack2(av[s].w, av[s].z);
            *(uint2*)((char*)As + (size_t)(s * 16 + ar) * 144 + ac4 * 2) = p;
        }
        __syncthreads();
#pragma unroll
        for (int kk = 0; kk < 2; ++kk) {
            short8 af[4], bf[4];
#pragma unroll
            for (int tm = 0; tm < 4; ++tm) {
                int m = wm + tm * 16 + l15;
                af[tm] = *(const short8*)((const char*)As + (size_t)m * 144 + kk * 64 + quad * 16);
            }
#pragma unroll
            for (int tn = 0; tn < 4; ++tn) {
                int n = wn + tn * 16 + l15;
                int c = kk * 4 + quad;
                int slot = n * 8 + (c ^ (n & 7));
                bf[tn] = *(const short8*)(Bs + slot * 16);
            }
#pragma unroll
            for (int tm = 0; tm < 4; ++tm)
#pragma unroll
                for (int tn = 0; tn < 4; ++tn)
                    acc[tm][tn] = __builtin_amdgcn_mfma_f32_16x16x32_bf16(
                        af[tm], bf[tn], acc[tm][tn], 0, 0, 0);
        }
        __syncthreads();
    }
#pragma unroll
    for (int tn = 0; tn < 4; ++tn) {
        int col = bn + wn + tn * 16 + l15;
        float bias = beff[col];
#pragma unroll
        for (int tm = 0; tm < 4; ++tm) {
            int row0 = bm + wm + tm * 16 + quad * 4;
#pragma unroll
            for (int r = 0; r < 4; ++r)
                C[(size_t)(row0 + r) * 1024 + col] = acc[tm][tn][r] + bias;
        }
    }
}

extern "C" void kernel_launch(void* const* d_in, const int* in_sizes, int n_in,
                              void* d_out, int out_size, void* d_ws, size_t ws_size,
                              hipStream_t stream) {
    const float* tokens = (const float*)d_in[0];  // (4,2048,1024) fp32
    const float* W      = (const float*)d_in[1];  // (1024, 10240) fp32
    const float* b      = (const float*)d_in[2];  // (10240,) fp32
    float* out = (float*)d_out;                   // (4,2048,1024) fp32

    unsigned short* Wt = (unsigned short*)d_ws;                       // 2 MB bf16
    float* beff = (float*)((char*)d_ws + 2097152);                    // 4 KB fp32
    unsigned short* Ab = (unsigned short*)((char*)d_ws + 2101248);    // 16.8 MB bf16

    fold_w<<<dim3(16, 32), 256, 0, stream>>>(W, Wt);
    fold_b<<<1, 256, 0, stream>>>(b, beff);

    if (ws_size >= 2101248 + (size_t)8192 * 1024 * 2) {
        cvt_bf16<<<4096, 256, 0, stream>>>(tokens, (uint4*)Ab);
        gemm_bf16<<<dim3(64, 8), 256, 0, stream>>>(Ab, Wt, beff, out);
    } else {
        gemm_fb<<<dim3(8, 64), 256, 0, stream>>>(tokens, Wt, beff, out);
    }
}

// Round 3
// 130.997 us; speedup vs baseline: 1.0938x; 1.0368x over previous
//
#include <hip/hip_runtime.h>
#include <stdint.h>

// out = tokens @ W_eff + b_eff, where W_eff folds the BULK_DIM=10 depth
// dimension with closed-form weights w_k = (1/10) * sum_{z=k..10} 1/z.
// (The reference scan is the running mean; averaging over depth gives these.)

static constexpr float FW[10] = {
    0.2928968253968254f, 0.1928968253968254f, 0.1428968253968254f,
    0.1095634920634921f, 0.0845634920634921f, 0.0645634920634921f,
    0.0478968253968254f, 0.0336111111111111f, 0.0211111111111111f,
    0.0100000000000000f};

typedef __attribute__((ext_vector_type(8))) short short8;     // 8 bf16 = 4 VGPR
typedef __attribute__((ext_vector_type(4))) float floatx4;    // 16x16 C/D frag
typedef __attribute__((ext_vector_type(16))) float floatx16;  // 32x32 C/D frag

// round-to-nearest fp32->bf16, pack two into one uint via v_perm_b32
__device__ inline unsigned int bf16pack2(float hi, float lo) {
    unsigned int uh = __float_as_uint(hi) + 0x8000u;
    unsigned int ul = __float_as_uint(lo) + 0x8000u;
    return __builtin_amdgcn_perm(uh, ul, 0x07060302u);  // {hi[31:16], lo[31:16]}
}

#define LDS_AS(p) ((__attribute__((address_space(3))) unsigned int*)(p))
#define GLB_AS(p) ((const __attribute__((address_space(1))) unsigned int*)(p))

// ---------------------------------------------------------------------------
// Merged prep kernel (one launch, block-id partitioned):
//   blocks [0,512):    fold_w  W_eff^T[n][k] bf16, n-major (32k x 64n tiles)
//   block  512:        fold_b  b_eff fp32
//   blocks [513,4609): cvt     tokens fp32 -> bf16 (8 elems/thread)
// All HBM-bound; combined ~94 MB => ~16 us, replaces 3 serialized launches.
// ---------------------------------------------------------------------------
__global__ __launch_bounds__(256) void prep(const float* __restrict__ W,
                                            const float* __restrict__ tokens,
                                            const float* __restrict__ b,
                                            unsigned short* __restrict__ Wt,
                                            float* __restrict__ beff,
                                            uint4* __restrict__ Ab,
                                            int do_cvt) {
    __shared__ float T[32 * 65];
    const int t = threadIdx.x;
    const int bid = blockIdx.x;

    if (bid < 512) {  // ---- fold_w
        const int n0 = (bid & 15) * 64;
        const int k0 = (bid >> 4) * 32;
#pragma unroll
        for (int s = 0; s < 2; ++s) {
            int slot = s * 256 + t;
            int r = slot >> 4;              // k-local 0..31
            int c4 = (slot & 15) * 4;       // n-local float4
            const float4* src = (const float4*)(W + (size_t)(k0 + r) * 10240 + n0 + c4);
            float4 acc = {0.f, 0.f, 0.f, 0.f};
#pragma unroll
            for (int j = 0; j < 10; ++j) {
                float4 v = src[j * 256];
                acc.x += FW[j] * v.x; acc.y += FW[j] * v.y;
                acc.z += FW[j] * v.z; acc.w += FW[j] * v.w;
            }
            T[r * 65 + c4 + 0] = acc.x;
            T[r * 65 + c4 + 1] = acc.y;
            T[r * 65 + c4 + 2] = acc.z;
            T[r * 65 + c4 + 3] = acc.w;
        }
        __syncthreads();
#pragma unroll
        for (int s = 0; s < 2; ++s) {
            int slot = s * 256 + t;
            int nl = slot >> 3;             // n-local 0..63
            int k4 = (slot & 7) * 4;        // k-local group of 4
            float f0 = T[(k4 + 0) * 65 + nl];
            float f1 = T[(k4 + 1) * 65 + nl];
            float f2 = T[(k4 + 2) * 65 + nl];
            float f3 = T[(k4 + 3) * 65 + nl];
            uint2 p;
            p.x = bf16pack2(f1, f0);
            p.y = bf16pack2(f3, f2);
            *(uint2*)(Wt + (size_t)(n0 + nl) * 1024 + k0 + k4) = p;
        }
        return;
    }
    if (bid == 512) {  // ---- fold_b
        const float4* src = (const float4*)b + t;
        float4 acc = {0.f, 0.f, 0.f, 0.f};
#pragma unroll
        for (int j = 0; j < 10; ++j) {
            float4 v = src[j * 256];
            acc.x += FW[j] * v.x; acc.y += FW[j] * v.y;
            acc.z += FW[j] * v.z; acc.w += FW[j] * v.w;
        }
        ((float4*)beff)[t] = acc;
        return;
    }
    if (do_cvt) {  // ---- cvt tokens -> bf16
        size_t i = (size_t)(bid - 513) * 256 + t;
        const float4* src = (const float4*)tokens + i * 2;
        float4 a0 = src[0], a1 = src[1];
        uint4 p;
        p.x = bf16pack2(a0.y, a0.x);
        p.y = bf16pack2(a0.w, a0.z);
        p.z = bf16pack2(a1.y, a1.x);
        p.w = bf16pack2(a1.w, a1.z);
        Ab[i] = p;
    }
}

// ---------------------------------------------------------------------------
// GEMM: C[8192][1024] = Ab(bf16) @ Weff^T + b_eff
// 128x128 tile, 4 waves 2x2, each wave 64x64 = 2x2 of mfma_f32_32x32x16_bf16,
// BK=64 (4 kk-steps of K=16). Both operands via global_load_lds width=16,
// XOR swizzle slot = row*8 + (chunk ^ (row&7)).
// Fragments (32x32x16): A row = lane&31, k = 8*(lane>>5)+j (16B contiguous);
// B col = lane&31, same k. C/D: col = lane&31,
// row = (reg&3) + 8*(reg>>2) + 4*(lane>>5)  [m74/m101-verified].
// Grid (64,8), x = M-tile: id%8 = M-tile%8 pins A stripes per XCD;
// B (2 MB) is die-resident in L3 after first touch.
// ---------------------------------------------------------------------------
__global__ __launch_bounds__(256) void gemm32(const unsigned short* __restrict__ Ab,
                                              const unsigned short* __restrict__ Wt,
                                              const float* __restrict__ beff,
                                              float* __restrict__ C) {
    __shared__ __align__(16) unsigned char As[16384];  // 128 rows x 8 chunks x 16B
    __shared__ __align__(16) unsigned char Bs[16384];

    const int t = threadIdx.x;
    const int lane = t & 63;
    const int w = t >> 6;
    const int l31 = lane & 31;
    const int khalf = lane >> 5;       // 0/1: k-offset 0 or 8 within K=16
    const int wm = (w & 1) * 64;
    const int wn = (w >> 1) * 64;
    const int bm = blockIdx.x * 128;   // x fastest -> id%8 = M-tile%8 (XCD pin)
    const int bn = blockIdx.y * 128;

    floatx16 acc[2][2];
#pragma unroll
    for (int i = 0; i < 2; ++i)
#pragma unroll
        for (int j = 0; j < 2; ++j)
#pragma unroll
            for (int r = 0; r < 16; ++r) acc[i][j][r] = 0.f;

    const char* Abase = (const char*)Ab + (size_t)bm * 2048;
    const char* Bbase = (const char*)Wt + (size_t)bn * 2048;

    for (int k0 = 0; k0 < 1024; k0 += 64) {
#pragma unroll
        for (int i = 0; i < 4; ++i) {
            int I = w * 4 + i;              // 0..15
            int slot = I * 64 + lane;       // physical 16B slot 0..1023
            int m = slot >> 3;              // tile row 0..127
            int c = (slot & 7) ^ (m & 7);   // logical k-chunk (XOR swizzle)
            size_t off = (size_t)m * 2048 + (size_t)k0 * 2 + c * 16;
            __builtin_amdgcn_global_load_lds(GLB_AS(Abase + off), LDS_AS(As + I * 1024), 16, 0, 0);
            __builtin_amdgcn_global_load_lds(GLB_AS(Bbase + off), LDS_AS(Bs + I * 1024), 16, 0, 0);
        }
        __syncthreads();

#pragma unroll
        for (int kk = 0; kk < 4; ++kk) {
            int c = kk * 2 + khalf;        // logical chunk for this frag
            short8 af[2], bf[2];
#pragma unroll
            for (int tm = 0; tm < 2; ++tm) {
                int m = wm + tm * 32 + l31;
                int slot = m * 8 + (c ^ (m & 7));
                af[tm] = *(const short8*)(As + slot * 16);
            }
#pragma unroll
            for (int tn = 0; tn < 2; ++tn) {
                int n = wn + tn * 32 + l31;
                int slot = n * 8 + (c ^ (n & 7));
                bf[tn] = *(const short8*)(Bs + slot * 16);
            }
#pragma unroll
            for (int tm = 0; tm < 2; ++tm)
#pragma unroll
                for (int tn = 0; tn < 2; ++tn)
                    acc[tm][tn] = __builtin_amdgcn_mfma_f32_32x32x16_bf16(
                        af[tm], bf[tn], acc[tm][tn], 0, 0, 0);
        }
        __syncthreads();
    }

    // epilogue: col = lane&31, row = (reg&3) + 8*(reg>>2) + 4*(lane>>5)
#pragma unroll
    for (int tn = 0; tn < 2; ++tn) {
        int col = bn + wn + tn * 32 + l31;
        float bias = beff[col];
#pragma unroll
        for (int tm = 0; tm < 2; ++tm) {
            int rbase = bm + wm + tm * 32 + 4 * khalf;
#pragma unroll
            for (int r = 0; r < 16; ++r) {
                int row = rbase + (r & 3) + 8 * (r >> 2);
                C[(size_t)row * 1024 + col] = acc[tm][tn][r] + bias;
            }
        }
    }
}

// ---------------------------------------------------------------------------
// Fallback GEMM (fp32 A converted in-kernel) for small ws_size.
// ---------------------------------------------------------------------------
__global__ __launch_bounds__(256) void gemm_fb(const float* __restrict__ A,
                                               const unsigned short* __restrict__ Wt,
                                               const float* __restrict__ beff,
                                               float* __restrict__ C) {
    __shared__ __align__(16) unsigned short As[128 * 72];
    __shared__ __align__(16) unsigned char Bs[16384];

    const int t = threadIdx.x;
    const int lane = t & 63;
    const int w = t >> 6;
    const int quad = lane >> 4;
    const int l15 = lane & 15;
    const int wm = (w & 1) * 64;
    const int wn = (w >> 1) * 64;
    const int bm = blockIdx.y * 128;
    const int bn = blockIdx.x * 128;

    floatx4 acc[4][4];
#pragma unroll
    for (int i = 0; i < 4; ++i)
#pragma unroll
        for (int j = 0; j < 4; ++j) acc[i][j] = (floatx4){0.f, 0.f, 0.f, 0.f};

    const int ar = t >> 4;
    const int ac4 = (t & 15) * 4;
    const float* Abase = A + (size_t)(bm + ar) * 1024 + ac4;
    const char* WtB = (const char*)Wt;

    for (int k0 = 0; k0 < 1024; k0 += 64) {
#pragma unroll
        for (int i = 0; i < 4; ++i) {
            int I = w * 4 + i;
            int slot = I * 64 + lane;
            int nl = slot >> 3;
            int c = (slot & 7) ^ (nl & 7);
            const char* g = WtB + (size_t)(bn + nl) * 2048 + k0 * 2 + c * 16;
            __builtin_amdgcn_global_load_lds(GLB_AS(g), LDS_AS(Bs + I * 1024), 16, 0, 0);
        }
        float4 av[8];
#pragma unroll
        for (int s = 0; s < 8; ++s)
            av[s] = *(const float4*)(Abase + (size_t)(s * 16) * 1024 + k0);
#pragma unroll
        for (int s = 0; s < 8; ++s) {
            uint2 p;
            p.x = bf16pack2(av[s].y, av[s].x);
            p.y = bf16pack2(av[s].w, av[s].z);
            *(uint2*)((char*)As + (size_t)(s * 16 + ar) * 144 + ac4 * 2) = p;
        }
        __syncthreads();
#pragma unroll
        for (int kk = 0; kk < 2; ++kk) {
            short8 af[4], bf[4];
#pragma unroll
            for (int tm = 0; tm < 4; ++tm) {
                int m = wm + tm * 16 + l15;
                af[tm] = *(const short8*)((const char*)As + (size_t)m * 144 + kk * 64 + quad * 16);
            }
#pragma unroll
            for (int tn = 0; tn < 4; ++tn) {
                int n = wn + tn * 16 + l15;
                int c = kk * 4 + quad;
                int slot = n * 8 + (c ^ (n & 7));
                bf[tn] = *(const short8*)(Bs + slot * 16);
            }
#pragma unroll
            for (int tm = 0; tm < 4; ++tm)
#pragma unroll
                for (int tn = 0; tn < 4; ++tn)
                    acc[tm][tn] = __builtin_amdgcn_mfma_f32_16x16x32_bf16(
                        af[tm], bf[tn], acc[tm][tn], 0, 0, 0);
        }
        __syncthreads();
    }
#pragma unroll
    for (int tn = 0; tn < 4; ++tn) {
        int col = bn + wn + tn * 16 + l15;
        float bias = beff[col];
#pragma unroll
        for (int tm = 0; tm < 4; ++tm) {
            int row0 = bm + wm + tm * 16 + quad * 4;
#pragma unroll
            for (int r = 0; r < 4; ++r)
                C[(size_t)(row0 + r) * 1024 + col] = acc[tm][tn][r] + bias;
        }
    }
}

extern "C" void kernel_launch(void* const* d_in, const int* in_sizes, int n_in,
                              void* d_out, int out_size, void* d_ws, size_t ws_size,
                              hipStream_t stream) {
    const float* tokens = (const float*)d_in[0];  // (4,2048,1024) fp32
    const float* W      = (const float*)d_in[1];  // (1024, 10240) fp32
    const float* b      = (const float*)d_in[2];  // (10240,) fp32
    float* out = (float*)d_out;                   // (4,2048,1024) fp32

    unsigned short* Wt = (unsigned short*)d_ws;                       // 2 MB bf16
    float* beff = (float*)((char*)d_ws + 2097152);                    // 4 KB fp32
    unsigned short* Ab = (unsigned short*)((char*)d_ws + 2101248);    // 16.8 MB bf16

    const int big_ws = ws_size >= 2101248 + (size_t)8192 * 1024 * 2;

    if (big_ws) {
        prep<<<513 + 4096, 256, 0, stream>>>(W, tokens, b, Wt, beff, (uint4*)Ab, 1);
        gemm32<<<dim3(64, 8), 256, 0, stream>>>(Ab, Wt, beff, out);
    } else {
        prep<<<513, 256, 0, stream>>>(W, tokens, b, Wt, beff, (uint4*)Ab, 0);
        gemm_fb<<<dim3(8, 64), 256, 0, stream>>>(tokens, Wt, beff, out);
    }
}

// Round 4
// 129.802 us; speedup vs baseline: 1.1038x; 1.0092x over previous
//
#include <hip/hip_runtime.h>
#include <stdint.h>

// out = tokens @ W_eff + b_eff, where W_eff folds the BULK_DIM=10 depth
// dimension with closed-form weights w_k = (1/10) * sum_{z=k..10} 1/z.
// (The reference scan is the running mean; averaging over depth gives these.)

static constexpr float FW[10] = {
    0.2928968253968254f, 0.1928968253968254f, 0.1428968253968254f,
    0.1095634920634921f, 0.0845634920634921f, 0.0645634920634921f,
    0.0478968253968254f, 0.0336111111111111f, 0.0211111111111111f,
    0.0100000000000000f};

typedef __attribute__((ext_vector_type(8))) short short8;     // 8 bf16 = 4 VGPR
typedef __attribute__((ext_vector_type(4))) float floatx4;    // 16x16 C/D frag
typedef __attribute__((ext_vector_type(16))) float floatx16;  // 32x32 C/D frag

// round-to-nearest fp32->bf16, pack two into one uint via v_perm_b32
__device__ inline unsigned int bf16pack2(float hi, float lo) {
    unsigned int uh = __float_as_uint(hi) + 0x8000u;
    unsigned int ul = __float_as_uint(lo) + 0x8000u;
    return __builtin_amdgcn_perm(uh, ul, 0x07060302u);  // {hi[31:16], lo[31:16]}
}

#define LDS_AS(p) ((__attribute__((address_space(3))) unsigned int*)(p))
#define GLB_AS(p) ((const __attribute__((address_space(1))) unsigned int*)(p))

// ---------------------------------------------------------------------------
// Merged prep kernel (one launch, block-id partitioned):
//   blocks [0,512):    fold_w  W_eff^T[n][k] bf16, n-major (32k x 64n tiles)
//   block  512:        fold_b  b_eff fp32
//   blocks [513,4609): cvt     tokens fp32 -> bf16 (8 elems/thread)
// All HBM-bound; combined ~94 MB => ~15-16 us.
// ---------------------------------------------------------------------------
__global__ __launch_bounds__(256) void prep(const float* __restrict__ W,
                                            const float* __restrict__ tokens,
                                            const float* __restrict__ b,
                                            unsigned short* __restrict__ Wt,
                                            float* __restrict__ beff,
                                            uint4* __restrict__ Ab,
                                            int do_cvt) {
    __shared__ float T[32 * 65];
    const int t = threadIdx.x;
    const int bid = blockIdx.x;

    if (bid < 512) {  // ---- fold_w
        const int n0 = (bid & 15) * 64;
        const int k0 = (bid >> 4) * 32;
#pragma unroll
        for (int s = 0; s < 2; ++s) {
            int slot = s * 256 + t;
            int r = slot >> 4;              // k-local 0..31
            int c4 = (slot & 15) * 4;       // n-local float4
            const float4* src = (const float4*)(W + (size_t)(k0 + r) * 10240 + n0 + c4);
            float4 acc = {0.f, 0.f, 0.f, 0.f};
#pragma unroll
            for (int j = 0; j < 10; ++j) {
                float4 v = src[j * 256];
                acc.x += FW[j] * v.x; acc.y += FW[j] * v.y;
                acc.z += FW[j] * v.z; acc.w += FW[j] * v.w;
            }
            T[r * 65 + c4 + 0] = acc.x;
            T[r * 65 + c4 + 1] = acc.y;
            T[r * 65 + c4 + 2] = acc.z;
            T[r * 65 + c4 + 3] = acc.w;
        }
        __syncthreads();
#pragma unroll
        for (int s = 0; s < 2; ++s) {
            int slot = s * 256 + t;
            int nl = slot >> 3;             // n-local 0..63
            int k4 = (slot & 7) * 4;        // k-local group of 4
            float f0 = T[(k4 + 0) * 65 + nl];
            float f1 = T[(k4 + 1) * 65 + nl];
            float f2 = T[(k4 + 2) * 65 + nl];
            float f3 = T[(k4 + 3) * 65 + nl];
            uint2 p;
            p.x = bf16pack2(f1, f0);
            p.y = bf16pack2(f3, f2);
            *(uint2*)(Wt + (size_t)(n0 + nl) * 1024 + k0 + k4) = p;
        }
        return;
    }
    if (bid == 512) {  // ---- fold_b
        const float4* src = (const float4*)b + t;
        float4 acc = {0.f, 0.f, 0.f, 0.f};
#pragma unroll
        for (int j = 0; j < 10; ++j) {
            float4 v = src[j * 256];
            acc.x += FW[j] * v.x; acc.y += FW[j] * v.y;
            acc.z += FW[j] * v.z; acc.w += FW[j] * v.w;
        }
        ((float4*)beff)[t] = acc;
        return;
    }
    if (do_cvt) {  // ---- cvt tokens -> bf16
        size_t i = (size_t)(bid - 513) * 256 + t;
        const float4* src = (const float4*)tokens + i * 2;
        float4 a0 = src[0], a1 = src[1];
        uint4 p;
        p.x = bf16pack2(a0.y, a0.x);
        p.y = bf16pack2(a0.w, a0.z);
        p.z = bf16pack2(a1.y, a1.x);
        p.w = bf16pack2(a1.w, a1.z);
        Ab[i] = p;
    }
}

// ---------------------------------------------------------------------------
// GEMM: C[8192][1024] = Ab(bf16) @ Weff^T + b_eff
// 128x128 tile, 4 waves 2x2, each wave 64x64 = 2x2 of mfma_f32_32x32x16_bf16.
// BK=128: LDS 32KB+32KB (2 blocks/CU, grid-limited anyway), 8 K-iters ->
// half the barrier drains of BK=64, 32 MFMA per wave per barrier.
// Both operands via global_load_lds width=16. XOR swizzle (16 chunks/row):
// slot = row*16 + (chunk ^ (row&15)); fragment ds_read_b128 conflict-free,
// staging writes stride-1.
// Grid (64,8), x = M-tile: id%8 = M-tile%8 pins A stripes per XCD;
// B (2 MB) is die-resident after first touch.
// ---------------------------------------------------------------------------
__global__ __launch_bounds__(256) void gemm32(const unsigned short* __restrict__ Ab,
                                              const unsigned short* __restrict__ Wt,
                                              const float* __restrict__ beff,
                                              float* __restrict__ C) {
    __shared__ __align__(16) unsigned char As[32768];  // 128 rows x 16 chunks x 16B
    __shared__ __align__(16) unsigned char Bs[32768];

    const int t = threadIdx.x;
    const int lane = t & 63;
    const int w = t >> 6;
    const int l31 = lane & 31;
    const int khalf = lane >> 5;       // 0/1: k-offset 0 or 8 within K=16
    const int wm = (w & 1) * 64;
    const int wn = (w >> 1) * 64;
    const int bm = blockIdx.x * 128;   // x fastest -> id%8 = M-tile%8 (XCD pin)
    const int bn = blockIdx.y * 128;

    floatx16 acc[2][2];
#pragma unroll
    for (int i = 0; i < 2; ++i)
#pragma unroll
        for (int j = 0; j < 2; ++j)
#pragma unroll
            for (int r = 0; r < 16; ++r) acc[i][j][r] = 0.f;

    const char* Abase = (const char*)Ab + (size_t)bm * 2048;
    const char* Bbase = (const char*)Wt + (size_t)bn * 2048;

    for (int k0 = 0; k0 < 1024; k0 += 128) {
        // stage 32KB+32KB: 2048 slots each, 8 instr/wave per operand
#pragma unroll
        for (int i = 0; i < 8; ++i) {
            int I = w * 8 + i;              // 0..31
            int slot = I * 64 + lane;       // physical 16B slot 0..2047
            int m = slot >> 4;              // tile row 0..127
            int c = (slot & 15) ^ (m & 15); // logical k-chunk (XOR swizzle)
            size_t off = (size_t)m * 2048 + (size_t)k0 * 2 + c * 16;
            __builtin_amdgcn_global_load_lds(GLB_AS(Abase + off), LDS_AS(As + I * 1024), 16, 0, 0);
            __builtin_amdgcn_global_load_lds(GLB_AS(Bbase + off), LDS_AS(Bs + I * 1024), 16, 0, 0);
        }
        __syncthreads();

#pragma unroll
        for (int kk = 0; kk < 8; ++kk) {
            int c = kk * 2 + khalf;        // logical chunk 0..15
            short8 af[2], bf[2];
#pragma unroll
            for (int tm = 0; tm < 2; ++tm) {
                int m = wm + tm * 32 + l31;
                int slot = m * 16 + (c ^ (m & 15));
                af[tm] = *(const short8*)(As + slot * 16);
            }
#pragma unroll
            for (int tn = 0; tn < 2; ++tn) {
                int n = wn + tn * 32 + l31;
                int slot = n * 16 + (c ^ (n & 15));
                bf[tn] = *(const short8*)(Bs + slot * 16);
            }
#pragma unroll
            for (int tm = 0; tm < 2; ++tm)
#pragma unroll
                for (int tn = 0; tn < 2; ++tn)
                    acc[tm][tn] = __builtin_amdgcn_mfma_f32_32x32x16_bf16(
                        af[tm], bf[tn], acc[tm][tn], 0, 0, 0);
        }
        __syncthreads();
    }

    // epilogue: col = lane&31, row = (reg&3) + 8*(reg>>2) + 4*(lane>>5)
#pragma unroll
    for (int tn = 0; tn < 2; ++tn) {
        int col = bn + wn + tn * 32 + l31;
        float bias = beff[col];
#pragma unroll
        for (int tm = 0; tm < 2; ++tm) {
            int rbase = bm + wm + tm * 32 + 4 * khalf;
#pragma unroll
            for (int r = 0; r < 16; ++r) {
                int row = rbase + (r & 3) + 8 * (r >> 2);
                C[(size_t)row * 1024 + col] = acc[tm][tn][r] + bias;
            }
        }
    }
}

// ---------------------------------------------------------------------------
// Fallback GEMM (fp32 A converted in-kernel) for small ws_size.
// ---------------------------------------------------------------------------
__global__ __launch_bounds__(256) void gemm_fb(const float* __restrict__ A,
                                               const unsigned short* __restrict__ Wt,
                                               const float* __restrict__ beff,
                                               float* __restrict__ C) {
    __shared__ __align__(16) unsigned short As[128 * 72];
    __shared__ __align__(16) unsigned char Bs[16384];

    const int t = threadIdx.x;
    const int lane = t & 63;
    const int w = t >> 6;
    const int quad = lane >> 4;
    const int l15 = lane & 15;
    const int wm = (w & 1) * 64;
    const int wn = (w >> 1) * 64;
    const int bm = blockIdx.y * 128;
    const int bn = blockIdx.x * 128;

    floatx4 acc[4][4];
#pragma unroll
    for (int i = 0; i < 4; ++i)
#pragma unroll
        for (int j = 0; j < 4; ++j) acc[i][j] = (floatx4){0.f, 0.f, 0.f, 0.f};

    const int ar = t >> 4;
    const int ac4 = (t & 15) * 4;
    const float* Abase = A + (size_t)(bm + ar) * 1024 + ac4;
    const char* WtB = (const char*)Wt;

    for (int k0 = 0; k0 < 1024; k0 += 64) {
#pragma unroll
        for (int i = 0; i < 4; ++i) {
            int I = w * 4 + i;
            int slot = I * 64 + lane;
            int nl = slot >> 3;
            int c = (slot & 7) ^ (nl & 7);
            const char* g = WtB + (size_t)(bn + nl) * 2048 + k0 * 2 + c * 16;
            __builtin_amdgcn_global_load_lds(GLB_AS(g), LDS_AS(Bs + I * 1024), 16, 0, 0);
        }
        float4 av[8];
#pragma unroll
        for (int s = 0; s < 8; ++s)
            av[s] = *(const float4*)(Abase + (size_t)(s * 16) * 1024 + k0);
#pragma unroll
        for (int s = 0; s < 8; ++s) {
            uint2 p;
            p.x = bf16pack2(av[s].y, av[s].x);
            p.y = bf16pack2(av[s].w, av[s].z);
            *(uint2*)((char*)As + (size_t)(s * 16 + ar) * 144 + ac4 * 2) = p;
        }
        __syncthreads();
#pragma unroll
        for (int kk = 0; kk < 2; ++kk) {
            short8 af[4], bf[4];
#pragma unroll
            for (int tm = 0; tm < 4; ++tm) {
                int m = wm + tm * 16 + l15;
                af[tm] = *(const short8*)((const char*)As + (size_t)m * 144 + kk * 64 + quad * 16);
            }
#pragma unroll
            for (int tn = 0; tn < 4; ++tn) {
                int n = wn + tn * 16 + l15;
                int c = kk * 4 + quad;
                int slot = n * 8 + (c ^ (n & 7));
                bf[tn] = *(const short8*)(Bs + slot * 16);
            }
#pragma unroll
            for (int tm = 0; tm < 4; ++tm)
#pragma unroll
                for (int tn = 0; tn < 4; ++tn)
                    acc[tm][tn] = __builtin_amdgcn_mfma_f32_16x16x32_bf16(
                        af[tm], bf[tn], acc[tm][tn], 0, 0, 0);
        }
        __syncthreads();
    }
#pragma unroll
    for (int tn = 0; tn < 4; ++tn) {
        int col = bn + wn + tn * 16 + l15;
        float bias = beff[col];
#pragma unroll
        for (int tm = 0; tm < 4; ++tm) {
            int row0 = bm + wm + tm * 16 + quad * 4;
#pragma unroll
            for (int r = 0; r < 4; ++r)
                C[(size_t)(row0 + r) * 1024 + col] = acc[tm][tn][r] + bias;
        }
    }
}

extern "C" void kernel_launch(void* const* d_in, const int* in_sizes, int n_in,
                              void* d_out, int out_size, void* d_ws, size_t ws_size,
                              hipStream_t stream) {
    const float* tokens = (const float*)d_in[0];  // (4,2048,1024) fp32
    const float* W      = (const float*)d_in[1];  // (1024, 10240) fp32
    const float* b      = (const float*)d_in[2];  // (10240,) fp32
    float* out = (float*)d_out;                   // (4,2048,1024) fp32

    unsigned short* Wt = (unsigned short*)d_ws;                       // 2 MB bf16
    float* beff = (float*)((char*)d_ws + 2097152);                    // 4 KB fp32
    unsigned short* Ab = (unsigned short*)((char*)d_ws + 2101248);    // 16.8 MB bf16

    const int big_ws = ws_size >= 2101248 + (size_t)8192 * 1024 * 2;

    if (big_ws) {
        prep<<<513 + 4096, 256, 0, stream>>>(W, tokens, b, Wt, beff, (uint4*)Ab, 1);
        gemm32<<<dim3(64, 8), 256, 0, stream>>>(Ab, Wt, beff, out);
    } else {
        prep<<<513, 256, 0, stream>>>(W, tokens, b, Wt, beff, (uint4*)Ab, 0);
        gemm_fb<<<dim3(8, 64), 256, 0, stream>>>(tokens, Wt, beff, out);
    }
}

// Round 5
// 129.235 us; speedup vs baseline: 1.1087x; 1.0044x over previous
//
#include <hip/hip_runtime.h>
#include <stdint.h>

// out = tokens @ W_eff + b_eff, where W_eff folds the BULK_DIM=10 depth
// dimension with closed-form weights w_k = (1/10) * sum_{z=k..10} 1/z.
// (The reference scan is the running mean; averaging over depth gives these.)

static constexpr float FW[10] = {
    0.2928968253968254f, 0.1928968253968254f, 0.1428968253968254f,
    0.1095634920634921f, 0.0845634920634921f, 0.0645634920634921f,
    0.0478968253968254f, 0.0336111111111111f, 0.0211111111111111f,
    0.0100000000000000f};

typedef __attribute__((ext_vector_type(8))) short short8;     // 8 bf16 = 4 VGPR
typedef __attribute__((ext_vector_type(4))) float floatx4;    // 16x16 C/D frag
typedef __attribute__((ext_vector_type(16))) float floatx16;  // 32x32 C/D frag

// round-to-nearest fp32->bf16, pack two into one uint via v_perm_b32
__device__ inline unsigned int bf16pack2(float hi, float lo) {
    unsigned int uh = __float_as_uint(hi) + 0x8000u;
    unsigned int ul = __float_as_uint(lo) + 0x8000u;
    return __builtin_amdgcn_perm(uh, ul, 0x07060302u);  // {hi[31:16], lo[31:16]}
}

#define LDS_AS(p) ((__attribute__((address_space(3))) unsigned int*)(p))
#define GLB_AS(p) ((const __attribute__((address_space(1))) unsigned int*)(p))

// ---------------------------------------------------------------------------
// Merged prep kernel (one launch, block-id partitioned):
//   blocks [0,512):    fold_w  W_eff^T[n][k] bf16, n-major (32k x 64n tiles)
//   block  512:        fold_b  b_eff fp32
//   blocks [513,4609): cvt     tokens fp32 -> bf16 (8 elems/thread)
// All HBM-bound; combined ~94 MB => ~15-16 us.
// ---------------------------------------------------------------------------
__global__ __launch_bounds__(256) void prep(const float* __restrict__ W,
                                            const float* __restrict__ tokens,
                                            const float* __restrict__ b,
                                            unsigned short* __restrict__ Wt,
                                            float* __restrict__ beff,
                                            uint4* __restrict__ Ab,
                                            int do_cvt) {
    __shared__ float T[32 * 65];
    const int t = threadIdx.x;
    const int bid = blockIdx.x;

    if (bid < 512) {  // ---- fold_w
        const int n0 = (bid & 15) * 64;
        const int k0 = (bid >> 4) * 32;
#pragma unroll
        for (int s = 0; s < 2; ++s) {
            int slot = s * 256 + t;
            int r = slot >> 4;              // k-local 0..31
            int c4 = (slot & 15) * 4;       // n-local float4
            const float4* src = (const float4*)(W + (size_t)(k0 + r) * 10240 + n0 + c4);
            float4 acc = {0.f, 0.f, 0.f, 0.f};
#pragma unroll
            for (int j = 0; j < 10; ++j) {
                float4 v = src[j * 256];
                acc.x += FW[j] * v.x; acc.y += FW[j] * v.y;
                acc.z += FW[j] * v.z; acc.w += FW[j] * v.w;
            }
            T[r * 65 + c4 + 0] = acc.x;
            T[r * 65 + c4 + 1] = acc.y;
            T[r * 65 + c4 + 2] = acc.z;
            T[r * 65 + c4 + 3] = acc.w;
        }
        __syncthreads();
#pragma unroll
        for (int s = 0; s < 2; ++s) {
            int slot = s * 256 + t;
            int nl = slot >> 3;             // n-local 0..63
            int k4 = (slot & 7) * 4;        // k-local group of 4
            float f0 = T[(k4 + 0) * 65 + nl];
            float f1 = T[(k4 + 1) * 65 + nl];
            float f2 = T[(k4 + 2) * 65 + nl];
            float f3 = T[(k4 + 3) * 65 + nl];
            uint2 p;
            p.x = bf16pack2(f1, f0);
            p.y = bf16pack2(f3, f2);
            *(uint2*)(Wt + (size_t)(n0 + nl) * 1024 + k0 + k4) = p;
        }
        return;
    }
    if (bid == 512) {  // ---- fold_b
        const float4* src = (const float4*)b + t;
        float4 acc = {0.f, 0.f, 0.f, 0.f};
#pragma unroll
        for (int j = 0; j < 10; ++j) {
            float4 v = src[j * 256];
            acc.x += FW[j] * v.x; acc.y += FW[j] * v.y;
            acc.z += FW[j] * v.z; acc.w += FW[j] * v.w;
        }
        ((float4*)beff)[t] = acc;
        return;
    }
    if (do_cvt) {  // ---- cvt tokens -> bf16
        size_t i = (size_t)(bid - 513) * 256 + t;
        const float4* src = (const float4*)tokens + i * 2;
        float4 a0 = src[0], a1 = src[1];
        uint4 p;
        p.x = bf16pack2(a0.y, a0.x);
        p.y = bf16pack2(a0.w, a0.z);
        p.z = bf16pack2(a1.y, a1.x);
        p.w = bf16pack2(a1.w, a1.z);
        Ab[i] = p;
    }
}

// ---------------------------------------------------------------------------
// GEMM: C[8192][1024] = Ab(bf16) @ Weff^T + b_eff
// 128x128 tile, 4 waves 2x2, each wave 64x64 = 2x2 of mfma_f32_32x32x16_bf16.
// BK=64, DOUBLE-BUFFERED LDS (2 x 16KB per operand = 64KB/block, 2 blocks/CU).
// Pipeline order per iter: barrier -> issue prefetch(tile k+1) -> compute(k).
// The compiler's vmcnt(0) drain before the NEXT barrier then waits on loads
// issued a full compute phase earlier -> drain hidden (vs m97 structure where
// loads are issued right before the barrier).
// XOR swizzle slot = row*8 + (chunk ^ (row&7)); frag ds_read_b128 2-way free.
// Grid (64,8), x = M-tile: id%8 = M-tile%8 pins A stripes per XCD.
// ---------------------------------------------------------------------------
__global__ __launch_bounds__(256) void gemm32(const unsigned short* __restrict__ Ab,
                                              const unsigned short* __restrict__ Wt,
                                              const float* __restrict__ beff,
                                              float* __restrict__ C) {
    __shared__ __align__(16) unsigned char As[2][16384];  // 128 rows x 8 chunks x 16B
    __shared__ __align__(16) unsigned char Bs[2][16384];

    const int t = threadIdx.x;
    const int lane = t & 63;
    const int w = t >> 6;
    const int l31 = lane & 31;
    const int khalf = lane >> 5;       // 0/1: k-offset 0 or 8 within K=16
    const int wm = (w & 1) * 64;
    const int wn = (w >> 1) * 64;
    const int bm = blockIdx.x * 128;   // x fastest -> id%8 = M-tile%8 (XCD pin)
    const int bn = blockIdx.y * 128;

    floatx16 acc[2][2];
#pragma unroll
    for (int i = 0; i < 2; ++i)
#pragma unroll
        for (int j = 0; j < 2; ++j)
#pragma unroll
            for (int r = 0; r < 16; ++r) acc[i][j][r] = 0.f;

    const char* Abase = (const char*)Ab + (size_t)bm * 2048;
    const char* Bbase = (const char*)Wt + (size_t)bn * 2048;

    // staging: 1024 slots of 16B per operand, 4 instr/wave each
    const int sI = w * 4;  // this wave's first LDS row-group

    // prologue: stage tile 0 into buffer 0
#pragma unroll
    for (int i = 0; i < 4; ++i) {
        int I = sI + i;
        int slot = I * 64 + lane;
        int m = slot >> 3;
        int c = (slot & 7) ^ (m & 7);
        size_t off = (size_t)m * 2048 + c * 16;
        __builtin_amdgcn_global_load_lds(GLB_AS(Abase + off), LDS_AS(As[0] + I * 1024), 16, 0, 0);
        __builtin_amdgcn_global_load_lds(GLB_AS(Bbase + off), LDS_AS(Bs[0] + I * 1024), 16, 0, 0);
    }

#pragma unroll
    for (int kt = 0; kt < 16; ++kt) {
        __syncthreads();  // tile kt staged (prefetched a full compute phase ago)

        if (kt < 15) {    // prefetch tile kt+1 into the other buffer
            int k0n = (kt + 1) * 64;
            int buf = (kt + 1) & 1;
#pragma unroll
            for (int i = 0; i < 4; ++i) {
                int I = sI + i;
                int slot = I * 64 + lane;
                int m = slot >> 3;
                int c = (slot & 7) ^ (m & 7);
                size_t off = (size_t)m * 2048 + (size_t)k0n * 2 + c * 16;
                __builtin_amdgcn_global_load_lds(GLB_AS(Abase + off), LDS_AS(As[buf] + I * 1024), 16, 0, 0);
                __builtin_amdgcn_global_load_lds(GLB_AS(Bbase + off), LDS_AS(Bs[buf] + I * 1024), 16, 0, 0);
            }
        }

        const unsigned char* Acur = As[kt & 1];
        const unsigned char* Bcur = Bs[kt & 1];
#pragma unroll
        for (int kk = 0; kk < 4; ++kk) {
            int c = kk * 2 + khalf;        // logical chunk 0..7
            short8 af[2], bf[2];
#pragma unroll
            for (int tm = 0; tm < 2; ++tm) {
                int m = wm + tm * 32 + l31;
                int slot = m * 8 + (c ^ (m & 7));
                af[tm] = *(const short8*)(Acur + slot * 16);
            }
#pragma unroll
            for (int tn = 0; tn < 2; ++tn) {
                int n = wn + tn * 32 + l31;
                int slot = n * 8 + (c ^ (n & 7));
                bf[tn] = *(const short8*)(Bcur + slot * 16);
            }
#pragma unroll
            for (int tm = 0; tm < 2; ++tm)
#pragma unroll
                for (int tn = 0; tn < 2; ++tn)
                    acc[tm][tn] = __builtin_amdgcn_mfma_f32_32x32x16_bf16(
                        af[tm], bf[tn], acc[tm][tn], 0, 0, 0);
        }
    }

    // epilogue: col = lane&31, row = (reg&3) + 8*(reg>>2) + 4*(lane>>5)
#pragma unroll
    for (int tn = 0; tn < 2; ++tn) {
        int col = bn + wn + tn * 32 + l31;
        float bias = beff[col];
#pragma unroll
        for (int tm = 0; tm < 2; ++tm) {
            int rbase = bm + wm + tm * 32 + 4 * khalf;
#pragma unroll
            for (int r = 0; r < 16; ++r) {
                int row = rbase + (r & 3) + 8 * (r >> 2);
                C[(size_t)row * 1024 + col] = acc[tm][tn][r] + bias;
            }
        }
    }
}

// ---------------------------------------------------------------------------
// Fallback GEMM (fp32 A converted in-kernel) for small ws_size.
// ---------------------------------------------------------------------------
__global__ __launch_bounds__(256) void gemm_fb(const float* __restrict__ A,
                                               const unsigned short* __restrict__ Wt,
                                               const float* __restrict__ beff,
                                               float* __restrict__ C) {
    __shared__ __align__(16) unsigned short As[128 * 72];
    __shared__ __align__(16) unsigned char Bs[16384];

    const int t = threadIdx.x;
    const int lane = t & 63;
    const int w = t >> 6;
    const int quad = lane >> 4;
    const int l15 = lane & 15;
    const int wm = (w & 1) * 64;
    const int wn = (w >> 1) * 64;
    const int bm = blockIdx.y * 128;
    const int bn = blockIdx.x * 128;

    floatx4 acc[4][4];
#pragma unroll
    for (int i = 0; i < 4; ++i)
#pragma unroll
        for (int j = 0; j < 4; ++j) acc[i][j] = (floatx4){0.f, 0.f, 0.f, 0.f};

    const int ar = t >> 4;
    const int ac4 = (t & 15) * 4;
    const float* Abase = A + (size_t)(bm + ar) * 1024 + ac4;
    const char* WtB = (const char*)Wt;

    for (int k0 = 0; k0 < 1024; k0 += 64) {
#pragma unroll
        for (int i = 0; i < 4; ++i) {
            int I = w * 4 + i;
            int slot = I * 64 + lane;
            int nl = slot >> 3;
            int c = (slot & 7) ^ (nl & 7);
            const char* g = WtB + (size_t)(bn + nl) * 2048 + k0 * 2 + c * 16;
            __builtin_amdgcn_global_load_lds(GLB_AS(g), LDS_AS(Bs + I * 1024), 16, 0, 0);
        }
        float4 av[8];
#pragma unroll
        for (int s = 0; s < 8; ++s)
            av[s] = *(const float4*)(Abase + (size_t)(s * 16) * 1024 + k0);
#pragma unroll
        for (int s = 0; s < 8; ++s) {
            uint2 p;
            p.x = bf16pack2(av[s].y, av[s].x);
            p.y = bf16pack2(av[s].w, av[s].z);
            *(uint2*)((char*)As + (size_t)(s * 16 + ar) * 144 + ac4 * 2) = p;
        }
        __syncthreads();
#pragma unroll
        for (int kk = 0; kk < 2; ++kk) {
            short8 af[4], bf[4];
#pragma unroll
            for (int tm = 0; tm < 4; ++tm) {
                int m = wm + tm * 16 + l15;
                af[tm] = *(const short8*)((const char*)As + (size_t)m * 144 + kk * 64 + quad * 16);
            }
#pragma unroll
            for (int tn = 0; tn < 4; ++tn) {
                int n = wn + tn * 16 + l15;
                int c = kk * 4 + quad;
                int slot = n * 8 + (c ^ (n & 7));
                bf[tn] = *(const short8*)(Bs + slot * 16);
            }
#pragma unroll
            for (int tm = 0; tm < 4; ++tm)
#pragma unroll
                for (int tn = 0; tn < 4; ++tn)
                    acc[tm][tn] = __builtin_amdgcn_mfma_f32_16x16x32_bf16(
                        af[tm], bf[tn], acc[tm][tn], 0, 0, 0);
        }
        __syncthreads();
    }
#pragma unroll
    for (int tn = 0; tn < 4; ++tn) {
        int col = bn + wn + tn * 16 + l15;
        float bias = beff[col];
#pragma unroll
        for (int tm = 0; tm < 4; ++tm) {
            int row0 = bm + wm + tm * 16 + quad * 4;
#pragma unroll
            for (int r = 0; r < 4; ++r)
                C[(size_t)(row0 + r) * 1024 + col] = acc[tm][tn][r] + bias;
        }
    }
}

extern "C" void kernel_launch(void* const* d_in, const int* in_sizes, int n_in,
                              void* d_out, int out_size, void* d_ws, size_t ws_size,
                              hipStream_t stream) {
    const float* tokens = (const float*)d_in[0];  // (4,2048,1024) fp32
    const float* W      = (const float*)d_in[1];  // (1024, 10240) fp32
    const float* b      = (const float*)d_in[2];  // (10240,) fp32
    float* out = (float*)d_out;                   // (4,2048,1024) fp32

    unsigned short* Wt = (unsigned short*)d_ws;                       // 2 MB bf16
    float* beff = (float*)((char*)d_ws + 2097152);                    // 4 KB fp32
    unsigned short* Ab = (unsigned short*)((char*)d_ws + 2101248);    // 16.8 MB bf16

    const int big_ws = ws_size >= 2101248 + (size_t)8192 * 1024 * 2;

    if (big_ws) {
        prep<<<513 + 4096, 256, 0, stream>>>(W, tokens, b, Wt, beff, (uint4*)Ab, 1);
        gemm32<<<dim3(64, 8), 256, 0, stream>>>(Ab, Wt, beff, out);
    } else {
        prep<<<513, 256, 0, stream>>>(W, tokens, b, Wt, beff, (uint4*)Ab, 0);
        gemm_fb<<<dim3(8, 64), 256, 0, stream>>>(tokens, Wt, beff, out);
    }
}